// Round 1
// baseline (257.251 us; speedup 1.0000x reference)
//
#include <hip/hip_runtime.h>

#define IN_DIM 256
#define OUT_DIM 128
#define LEAKY 0.01f

// ---------------------------------------------------------------------------
// Kernel 1: support = LeakyReLU(features @ W^T)
// 256 threads/block, tile = 64 rows x 128 cols, KT = 32.
// fp32 vector-ALU GEMM (no fp32 MFMA on CDNA4).
// Thread (ty,tx): ty=t/32 owns rows ty*8..ty*8+7, tx=t%32 owns cols {tx,tx+32,tx+64,tx+96}.
// w_lds padded +1 -> strided-col scalar reads are bank-conflict-free
//   (stride 33 ≡ 1 mod 32 -> bank = (tx + k) % 32, all 32 lanes distinct).
// feat_lds reads are wave-broadcast (2 distinct addresses per wave).
// ---------------------------------------------------------------------------
__global__ __launch_bounds__(256) void gemm_leaky(
    const float* __restrict__ feat, const float* __restrict__ w,
    float* __restrict__ support, int nrows) {
  __shared__ float flds[64][36];   // pad 4 keeps float4 stores 16B-aligned
  __shared__ float wlds[128][33];  // pad 1 for conflict-free reads

  const int t  = threadIdx.x;
  const int tx = t & 31;
  const int ty = t >> 5;
  const int row0 = blockIdx.x * 64;

  float acc[8][4];
#pragma unroll
  for (int i = 0; i < 8; ++i)
#pragma unroll
    for (int j = 0; j < 4; ++j) acc[i][j] = 0.f;

  for (int kb = 0; kb < IN_DIM; kb += 32) {
    // stage features: 64 rows x 32 k = 512 float4, 2 per thread (coalesced)
#pragma unroll
    for (int i = 0; i < 2; ++i) {
      int q  = t + i * 256;
      int r  = q >> 3;
      int k4 = q & 7;
      int gr = row0 + r;
      if (gr >= nrows) gr = nrows - 1;  // clamp (stores are guarded later)
      const float4 v =
          *reinterpret_cast<const float4*>(&feat[gr * IN_DIM + kb + k4 * 4]);
      *reinterpret_cast<float4*>(&flds[r][k4 * 4]) = v;
    }
    // stage weight: 128 c x 32 k = 1024 float4, 4 per thread (coalesced read,
    // scalar stores because pad-1 breaks 16B alignment)
#pragma unroll
    for (int i = 0; i < 4; ++i) {
      int q  = t + i * 256;
      int c  = q >> 3;
      int k4 = q & 7;
      const float4 v =
          *reinterpret_cast<const float4*>(&w[c * IN_DIM + kb + k4 * 4]);
      wlds[c][k4 * 4 + 0] = v.x;
      wlds[c][k4 * 4 + 1] = v.y;
      wlds[c][k4 * 4 + 2] = v.z;
      wlds[c][k4 * 4 + 3] = v.w;
    }
    __syncthreads();

#pragma unroll
    for (int k = 0; k < 32; ++k) {
      float wv[4], fv[8];
#pragma unroll
      for (int j = 0; j < 4; ++j) wv[j] = wlds[tx + 32 * j][k];
#pragma unroll
      for (int i = 0; i < 8; ++i) fv[i] = flds[ty * 8 + i][k];
#pragma unroll
      for (int i = 0; i < 8; ++i)
#pragma unroll
        for (int j = 0; j < 4; ++j) acc[i][j] += fv[i] * wv[j];
    }
    __syncthreads();
  }

#pragma unroll
  for (int i = 0; i < 8; ++i) {
    int gr = row0 + ty * 8 + i;
    if (gr < nrows) {
#pragma unroll
      for (int j = 0; j < 4; ++j) {
        float v = acc[i][j];
        v = v > 0.f ? v : LEAKY * v;
        support[gr * OUT_DIM + tx + 32 * j] = v;
      }
    }
  }
}

// ---------------------------------------------------------------------------
// Kernel 2: out[r] = sum over edges (r,c,v) of v * support[c]
// edge_rows is SORTED -> per-row contiguous edge ranges found by binary search
// (9 lower_bounds per block, kept in LDS; no row_ptr scratch needed).
// 256 threads = 8 rows x 32 lanes; each lane accumulates 4 cols via float4.
// ---------------------------------------------------------------------------
__global__ __launch_bounds__(256) void spmm_sorted(
    const int* __restrict__ erows, const int* __restrict__ ecols,
    const float* __restrict__ evals, const float* __restrict__ support,
    float* __restrict__ out, int nrows, int nedges) {
  __shared__ int bounds[9];
  const int t    = threadIdx.x;
  const int row0 = blockIdx.x * 8;

  if (t < 9) {
    int target = row0 + t;
    int lo = 0, hi = nedges;
    while (lo < hi) {  // lower_bound: first i with erows[i] >= target
      int mid = (lo + hi) >> 1;
      if (erows[mid] < target) lo = mid + 1; else hi = mid;
    }
    bounds[t] = lo;
  }
  __syncthreads();

  const int lr   = t >> 5;
  const int lane = t & 31;
  const int row  = row0 + lr;
  if (row >= nrows) return;

  const int s = bounds[lr];
  const int e = bounds[lr + 1];

  float4 acc = {0.f, 0.f, 0.f, 0.f};
  for (int i = s; i < e; ++i) {
    const int   c = ecols[i];
    const float v = evals[i];
    const float4 sv =
        *reinterpret_cast<const float4*>(&support[c * OUT_DIM + lane * 4]);
    acc.x += v * sv.x;
    acc.y += v * sv.y;
    acc.z += v * sv.z;
    acc.w += v * sv.w;
  }
  *reinterpret_cast<float4*>(&out[row * OUT_DIM + lane * 4]) = acc;
}

// ---------------------------------------------------------------------------
extern "C" void kernel_launch(void* const* d_in, const int* in_sizes, int n_in,
                              void* d_out, int out_size, void* d_ws,
                              size_t ws_size, hipStream_t stream) {
  const float* features = (const float*)d_in[0];
  const float* weight   = (const float*)d_in[1];
  const int*   erows    = (const int*)d_in[2];
  const int*   ecols    = (const int*)d_in[3];
  const float* evals    = (const float*)d_in[4];
  float*       out      = (float*)d_out;

  const int nrows  = in_sizes[0] / IN_DIM;  // 100000
  const int nedges = in_sizes[2];           // 1600000

  // workspace: support [nrows, OUT_DIM] f32 = 51.2 MB
  float* support = (float*)d_ws;

  gemm_leaky<<<(nrows + 63) / 64, 256, 0, stream>>>(features, weight, support,
                                                    nrows);
  spmm_sorted<<<(nrows + 7) / 8, 256, 0, stream>>>(erows, ecols, evals,
                                                   support, out, nrows, nedges);
}

// Round 2
// 213.600 us; speedup vs baseline: 1.2044x; 1.2044x over previous
//
#include <hip/hip_runtime.h>

#define IN_DIM 256
#define OUT_DIM 128
#define LEAKY 0.01f

typedef __attribute__((ext_vector_type(8))) short bf16x8;
typedef __attribute__((ext_vector_type(4))) float f32x4;

union frag_u {
  bf16x8 v;
  unsigned u[4];
};

// RNE f32->bf16 pack (2 at a time). No builtin on gfx950 -> inline asm.
__device__ inline unsigned cvtpk_bf16(float lo, float hi) {
  unsigned r;
  asm volatile("v_cvt_pk_bf16_f32 %0, %1, %2" : "=v"(r) : "v"(lo), "v"(hi));
  return r;
}

__device__ inline float b2f(unsigned short u) {
  union { unsigned u; float f; } c;
  c.u = ((unsigned)u) << 16;
  return c.f;
}

// ---------------------------------------------------------------------------
// Kernel 0: weight fp32 [128*256] -> bf16 bits. 16384 threads x 2 elems.
// ---------------------------------------------------------------------------
__global__ __launch_bounds__(256) void wcvt(const float* __restrict__ w,
                                            unsigned* __restrict__ wbf) {
  int i = blockIdx.x * 256 + threadIdx.x;  // 16384 = 128*256/2
  float2 v = reinterpret_cast<const float2*>(w)[i];
  wbf[i] = cvtpk_bf16(v.x, v.y);
}

// ---------------------------------------------------------------------------
// Kernel 1: support(bf16) = LeakyReLU(features @ W^T) via bf16 MFMA.
// 4 waves/block, each wave: 16 rows x 128 cols, K=256 in 8 steps of 32.
// Swapped operands: D = mfma(Wfrag, Ffrag) => D[n][m], lane holds
// support[m0+(lane&15)][nt*16 + (lane>>4)*4 + r] -> 4 contiguous cols,
// stored as one 8B bf16x4 write. No LDS.
// A-frag (weight): lane = W[nt*16+(l&15)][k0+(l>>4)*8+j]  (16B global load)
// B-frag (feat):   lane = F[m0+(l&15)][k0+(l>>4)*8+j]     (2x float4 + cvt)
// ---------------------------------------------------------------------------
__global__ __launch_bounds__(256) void gemm_mfma(
    const float* __restrict__ feat, const unsigned short* __restrict__ wbf,
    unsigned short* __restrict__ support, int nrows) {
  const int wid  = threadIdx.x >> 6;
  const int lane = threadIdx.x & 63;
  const int lrow = lane & 15;
  const int hi   = lane >> 4;
  const int m0   = blockIdx.x * 64 + wid * 16;
  const int mrow = m0 + lrow;
  const int mr   = mrow < nrows ? mrow : nrows - 1;

  const float*          fp = feat + mr * IN_DIM + hi * 8;
  const unsigned short* wp = wbf + lrow * IN_DIM + hi * 8;

  f32x4 acc[8];
#pragma unroll
  for (int nt = 0; nt < 8; ++nt) acc[nt] = (f32x4){0.f, 0.f, 0.f, 0.f};

#pragma unroll
  for (int ks = 0; ks < 8; ++ks) {
    const float4 f0 = *reinterpret_cast<const float4*>(fp + ks * 32);
    const float4 f1 = *reinterpret_cast<const float4*>(fp + ks * 32 + 4);
    frag_u bf;
    bf.u[0] = cvtpk_bf16(f0.x, f0.y);
    bf.u[1] = cvtpk_bf16(f0.z, f0.w);
    bf.u[2] = cvtpk_bf16(f1.x, f1.y);
    bf.u[3] = cvtpk_bf16(f1.z, f1.w);
#pragma unroll
    for (int nt = 0; nt < 8; ++nt) {
      const bf16x8 af =
          *reinterpret_cast<const bf16x8*>(wp + nt * 16 * IN_DIM + ks * 32);
      acc[nt] = __builtin_amdgcn_mfma_f32_16x16x32_bf16(af, bf.v, acc[nt],
                                                        0, 0, 0);
    }
  }

  if (mrow < nrows) {
    unsigned short* orow = support + mrow * OUT_DIM + hi * 4;
#pragma unroll
    for (int nt = 0; nt < 8; ++nt) {
      f32x4 v = acc[nt];
      float a0 = v[0] > 0.f ? v[0] : LEAKY * v[0];
      float a1 = v[1] > 0.f ? v[1] : LEAKY * v[1];
      float a2 = v[2] > 0.f ? v[2] : LEAKY * v[2];
      float a3 = v[3] > 0.f ? v[3] : LEAKY * v[3];
      uint2 st;
      st.x = cvtpk_bf16(a0, a1);
      st.y = cvtpk_bf16(a2, a3);
      *reinterpret_cast<uint2*>(orow + nt * 16) = st;
    }
  }
}

// ---------------------------------------------------------------------------
// Kernel 2: out[r] = sum over edges (r,c,v) of v * support_bf16[c]
// edge_rows sorted -> per-row ranges via 9 lower_bounds per block.
// 256 threads = 8 rows x 32 lanes; lane owns 4 cols, 8B ushort4 gathers.
// fp32 accumulate, fp32 out.
// ---------------------------------------------------------------------------
__global__ __launch_bounds__(256) void spmm_bf16(
    const int* __restrict__ erows, const int* __restrict__ ecols,
    const float* __restrict__ evals, const unsigned short* __restrict__ support,
    float* __restrict__ out, int nrows, int nedges) {
  __shared__ int bounds[9];
  const int t    = threadIdx.x;
  const int row0 = blockIdx.x * 8;

  if (t < 9) {
    int target = row0 + t;
    int lo = 0, hi = nedges;
    while (lo < hi) {
      int mid = (lo + hi) >> 1;
      if (erows[mid] < target) lo = mid + 1; else hi = mid;
    }
    bounds[t] = lo;
  }
  __syncthreads();

  const int lr   = t >> 5;
  const int lane = t & 31;
  const int row  = row0 + lr;
  if (row >= nrows) return;

  const int s = bounds[lr];
  const int e = bounds[lr + 1];

  float4 acc = {0.f, 0.f, 0.f, 0.f};
  for (int i = s; i < e; ++i) {
    const int   c = ecols[i];
    const float v = evals[i];
    const ushort4 u =
        *reinterpret_cast<const ushort4*>(&support[c * OUT_DIM + lane * 4]);
    acc.x += v * b2f(u.x);
    acc.y += v * b2f(u.y);
    acc.z += v * b2f(u.z);
    acc.w += v * b2f(u.w);
  }
  *reinterpret_cast<float4*>(&out[row * OUT_DIM + lane * 4]) = acc;
}

// ---------------------------------------------------------------------------
extern "C" void kernel_launch(void* const* d_in, const int* in_sizes, int n_in,
                              void* d_out, int out_size, void* d_ws,
                              size_t ws_size, hipStream_t stream) {
  const float* features = (const float*)d_in[0];
  const float* weight   = (const float*)d_in[1];
  const int*   erows    = (const int*)d_in[2];
  const int*   ecols    = (const int*)d_in[3];
  const float* evals    = (const float*)d_in[4];
  float*       out      = (float*)d_out;

  const int nrows  = in_sizes[0] / IN_DIM;  // 100000
  const int nedges = in_sizes[2];           // 1600000

  // ws layout: support bf16 [nrows*128] (25.6 MB), then wbf16 [128*256] (64KB)
  unsigned short* support = (unsigned short*)d_ws;
  unsigned short* wbf =
      (unsigned short*)((char*)d_ws + (size_t)nrows * OUT_DIM * 2);

  wcvt<<<64, 256, 0, stream>>>(weight, (unsigned*)wbf);
  gemm_mfma<<<(nrows + 63) / 64, 256, 0, stream>>>(features, wbf, support,
                                                   nrows);
  spmm_bf16<<<(nrows + 7) / 8, 256, 0, stream>>>(erows, ecols, evals, support,
                                                 out, nrows, nedges);
}

// Round 3
// 173.546 us; speedup vs baseline: 1.4823x; 1.2308x over previous
//
#include <hip/hip_runtime.h>

#define IN_DIM 256
#define OUT_DIM 128
#define LEAKY 0.01f

typedef __attribute__((ext_vector_type(8))) short bf16x8;
typedef __attribute__((ext_vector_type(4))) float f32x4;

union frag_u {
  bf16x8 v;
  unsigned u[4];
};

// RNE f32->bf16 pack (2 at a time). No builtin on gfx950 -> inline asm.
__device__ inline unsigned cvtpk_bf16(float lo, float hi) {
  unsigned r;
  asm volatile("v_cvt_pk_bf16_f32 %0, %1, %2" : "=v"(r) : "v"(lo), "v"(hi));
  return r;
}

__device__ inline float b2f(unsigned short u) {
  union { unsigned u; float f; } c;
  c.u = ((unsigned)u) << 16;
  return c.f;
}

// ---------------------------------------------------------------------------
// Kernel 0: weight fp32 [128*256] -> bf16 bits. 64 blocks x 256 thr x 2 elems.
// ---------------------------------------------------------------------------
__global__ __launch_bounds__(256) void wcvt(const float* __restrict__ w,
                                            unsigned* __restrict__ wbf) {
  int i = blockIdx.x * 256 + threadIdx.x;  // 16384 = 128*256/2
  float2 v = reinterpret_cast<const float2*>(w)[i];
  wbf[i] = cvtpk_bf16(v.x, v.y);
}

// ---------------------------------------------------------------------------
// Kernel 1: support(bf16) = LeakyReLU(features @ W^T) via bf16 MFMA.
// 4 waves/block, each wave: 16 rows x 128 cols, K=256 in 8 steps of 32.
// Swapped operands: D = mfma(Wfrag, Ffrag) => lane holds
// support[m0+(lane&15)][nt*16 + (lane>>4)*4 + r] -> 4 contiguous cols,
// one 8B bf16x4 store. No LDS.
// ---------------------------------------------------------------------------
__global__ __launch_bounds__(256) void gemm_mfma(
    const float* __restrict__ feat, const unsigned short* __restrict__ wbf,
    unsigned short* __restrict__ support, int nrows) {
  const int wid  = threadIdx.x >> 6;
  const int lane = threadIdx.x & 63;
  const int lrow = lane & 15;
  const int hi   = lane >> 4;
  const int m0   = blockIdx.x * 64 + wid * 16;
  const int mrow = m0 + lrow;
  const int mr   = mrow < nrows ? mrow : nrows - 1;

  const float*          fp = feat + mr * IN_DIM + hi * 8;
  const unsigned short* wp = wbf + lrow * IN_DIM + hi * 8;

  f32x4 acc[8];
#pragma unroll
  for (int nt = 0; nt < 8; ++nt) acc[nt] = (f32x4){0.f, 0.f, 0.f, 0.f};

#pragma unroll
  for (int ks = 0; ks < 8; ++ks) {
    const float4 f0 = *reinterpret_cast<const float4*>(fp + ks * 32);
    const float4 f1 = *reinterpret_cast<const float4*>(fp + ks * 32 + 4);
    frag_u bf;
    bf.u[0] = cvtpk_bf16(f0.x, f0.y);
    bf.u[1] = cvtpk_bf16(f0.z, f0.w);
    bf.u[2] = cvtpk_bf16(f1.x, f1.y);
    bf.u[3] = cvtpk_bf16(f1.z, f1.w);
#pragma unroll
    for (int nt = 0; nt < 8; ++nt) {
      const bf16x8 af =
          *reinterpret_cast<const bf16x8*>(wp + nt * 16 * IN_DIM + ks * 32);
      acc[nt] = __builtin_amdgcn_mfma_f32_16x16x32_bf16(af, bf.v, acc[nt],
                                                        0, 0, 0);
    }
  }

  if (mrow < nrows) {
    unsigned short* orow = support + mrow * OUT_DIM + hi * 4;
#pragma unroll
    for (int nt = 0; nt < 8; ++nt) {
      f32x4 v = acc[nt];
      float a0 = v[0] > 0.f ? v[0] : LEAKY * v[0];
      float a1 = v[1] > 0.f ? v[1] : LEAKY * v[1];
      float a2 = v[2] > 0.f ? v[2] : LEAKY * v[2];
      float a3 = v[3] > 0.f ? v[3] : LEAKY * v[3];
      uint2 st;
      st.x = cvtpk_bf16(a0, a1);
      st.y = cvtpk_bf16(a2, a3);
      *reinterpret_cast<uint2*>(orow + nt * 16) = st;
    }
  }
}

// ---------------------------------------------------------------------------
// Kernel 2: out[r] = sum over edges (r,c,v) of v * support_bf16[c]
// edge_rows sorted -> per-row ranges via 9 lower_bounds per block.
// 256 threads = 8 rows x 32 lanes; lane owns 4 cols (8B ushort4 gathers).
// UNROLL=8 with predicated clamped loads: 8 independent gathers in flight
// per wave-half -> latency-bound loop gets 8x MLP. Masked slots re-read
// edge e-1's line (L1-hit, value multiplied by 0).
// ---------------------------------------------------------------------------
__global__ __launch_bounds__(256) void spmm_bf16(
    const int* __restrict__ erows, const int* __restrict__ ecols,
    const float* __restrict__ evals, const unsigned short* __restrict__ support,
    float* __restrict__ out, int nrows, int nedges) {
  __shared__ int bounds[9];
  const int t    = threadIdx.x;
  const int row0 = blockIdx.x * 8;

  if (t < 9) {
    int target = row0 + t;
    int lo = 0, hi = nedges;
    while (lo < hi) {
      int mid = (lo + hi) >> 1;
      if (erows[mid] < target) lo = mid + 1; else hi = mid;
    }
    bounds[t] = lo;
  }
  __syncthreads();

  const int lr   = t >> 5;
  const int lane = t & 31;
  const int row  = row0 + lr;
  if (row >= nrows) return;

  const int s = bounds[lr];
  const int e = bounds[lr + 1];

  float4 acc[8];
#pragma unroll
  for (int j = 0; j < 8; ++j) acc[j] = (float4){0.f, 0.f, 0.f, 0.f};

  for (int i = s; i < e; i += 8) {
    int   ii[8];
    float vv[8];
#pragma unroll
    for (int j = 0; j < 8; ++j) {
      const int  idx = i + j;
      const bool ok  = idx < e;
      ii[j] = ok ? idx : e - 1;
      vv[j] = ok ? evals[ii[j]] : 0.f;
    }
#pragma unroll
    for (int j = 0; j < 8; ++j) {
      const int c = ecols[ii[j]];
      const ushort4 u =
          *reinterpret_cast<const ushort4*>(&support[c * OUT_DIM + lane * 4]);
      acc[j].x += vv[j] * b2f(u.x);
      acc[j].y += vv[j] * b2f(u.y);
      acc[j].z += vv[j] * b2f(u.z);
      acc[j].w += vv[j] * b2f(u.w);
    }
  }

#pragma unroll
  for (int j = 1; j < 8; ++j) {
    acc[0].x += acc[j].x;
    acc[0].y += acc[j].y;
    acc[0].z += acc[j].z;
    acc[0].w += acc[j].w;
  }
  *reinterpret_cast<float4*>(&out[row * OUT_DIM + lane * 4]) = acc[0];
}

// ---------------------------------------------------------------------------
extern "C" void kernel_launch(void* const* d_in, const int* in_sizes, int n_in,
                              void* d_out, int out_size, void* d_ws,
                              size_t ws_size, hipStream_t stream) {
  const float* features = (const float*)d_in[0];
  const float* weight   = (const float*)d_in[1];
  const int*   erows    = (const int*)d_in[2];
  const int*   ecols    = (const int*)d_in[3];
  const float* evals    = (const float*)d_in[4];
  float*       out      = (float*)d_out;

  const int nrows  = in_sizes[0] / IN_DIM;  // 100000
  const int nedges = in_sizes[2];           // 1600000

  // ws layout: support bf16 [nrows*128] (25.6 MB), then wbf16 [128*256] (64KB)
  unsigned short* support = (unsigned short*)d_ws;
  unsigned short* wbf =
      (unsigned short*)((char*)d_ws + (size_t)nrows * OUT_DIM * 2);

  wcvt<<<64, 256, 0, stream>>>(weight, (unsigned*)wbf);
  gemm_mfma<<<(nrows + 63) / 64, 256, 0, stream>>>(features, wbf, support,
                                                   nrows);
  spmm_bf16<<<(nrows + 7) / 8, 256, 0, stream>>>(erows, ecols, evals, support,
                                                 out, nrows, nedges);
}

// Round 4
// 133.016 us; speedup vs baseline: 1.9340x; 1.3047x over previous
//
#include <hip/hip_runtime.h>

#define IN_DIM 256
#define OUT_DIM 128
#define LEAKY 0.01f

typedef __attribute__((ext_vector_type(8))) short bf16x8;
typedef __attribute__((ext_vector_type(4))) float f32x4;

// RNE f32->bf16 pack (2 at a time). No builtin on gfx950 -> inline asm.
__device__ inline unsigned cvtpk_bf16(float lo, float hi) {
  unsigned r;
  asm volatile("v_cvt_pk_bf16_f32 %0, %1, %2" : "=v"(r) : "v"(lo), "v"(hi));
  return r;
}

__device__ inline float b2f(unsigned short u) {
  union { unsigned u; float f; } c;
  c.u = ((unsigned)u) << 16;
  return c.f;
}

// ---------------------------------------------------------------------------
// Kernel 0a: weight fp32 [128*256] -> bf16 bits.
// ---------------------------------------------------------------------------
__global__ __launch_bounds__(256) void wcvt(const float* __restrict__ w,
                                            unsigned* __restrict__ wbf) {
  int i = blockIdx.x * 256 + threadIdx.x;  // 16384 = 128*256/2
  float2 v = reinterpret_cast<const float2*>(w)[i];
  wbf[i] = cvtpk_bf16(v.x, v.y);
}

// ---------------------------------------------------------------------------
// Kernel 0b: row_starts[r] = lower_bound(erows, r), r in [0, nrows]; +sentinel.
// 100K independent binary searches, latency fully hidden across the grid.
// Moves the per-block serial search OFF the spmm critical path.
// ---------------------------------------------------------------------------
__global__ __launch_bounds__(256) void row_bounds(const int* __restrict__ erows,
                                                  int* __restrict__ rs,
                                                  int nrows, int nedges) {
  int r = blockIdx.x * 256 + threadIdx.x;
  if (r > nrows) return;
  if (r == nrows) { rs[nrows] = nedges; return; }
  int lo = 0, hi = nedges;
  while (lo < hi) {
    int mid = (lo + hi) >> 1;
    if (erows[mid] < r) lo = mid + 1; else hi = mid;
  }
  rs[r] = lo;
}

// ---------------------------------------------------------------------------
// Kernel 1: support(bf16) = LeakyReLU(features @ W^T) via bf16 MFMA.
// Block = 256 thr / 4 waves, 128 rows/block; wave = 32 rows (2x16 stripes)
// x 128 cols -> each W-fragment load feeds 2 MFMAs.
// Features staged coalesced f32 -> cvt -> bf16 LDS [128][256] (64 KB) with a
// 16-slot XOR swizzle on 16B units over a 256B period:
//   byte(r, cu) = r*512 + ((cu&16)<<4) + (((cu&15) ^ (r&15))<<4),  cu = k/8
// -> ds_read_b128: 16 lanes (same hi) hit 16 distinct 16B slots -> 2-way
//    aliasing across the wave = free (m136). Same formula on write & read.
// W (bf16, 64 KB) read direct from global: L2-hot, each 16B frag reused 2x.
// ---------------------------------------------------------------------------
__global__ __launch_bounds__(256) void gemm_mfma(
    const float* __restrict__ feat, const unsigned short* __restrict__ wbf,
    unsigned short* __restrict__ support, int nrows) {
  __shared__ unsigned short fbuf[128 * 256];  // 64 KB, swizzled

  const int t    = threadIdx.x;
  const int row0 = blockIdx.x * 128;
  char* fb = reinterpret_cast<char*>(fbuf);

  // stage: thread handles 16 groups of 8 consecutive floats (coalesced)
#pragma unroll 4
  for (int it = 0; it < 16; ++it) {
    const int g  = it * 256 + t;   // 0..4095
    const int r  = g >> 5;         // 0..127
    const int cu = g & 31;         // 16B-unit index = k/8
    int gr = row0 + r;
    if (gr >= nrows) gr = nrows - 1;
    const float4 a =
        *reinterpret_cast<const float4*>(&feat[gr * IN_DIM + cu * 8]);
    const float4 b =
        *reinterpret_cast<const float4*>(&feat[gr * IN_DIM + cu * 8 + 4]);
    uint4 pk;
    pk.x = cvtpk_bf16(a.x, a.y);
    pk.y = cvtpk_bf16(a.z, a.w);
    pk.z = cvtpk_bf16(b.x, b.y);
    pk.w = cvtpk_bf16(b.z, b.w);
    const int byte = r * 512 + ((cu & 16) << 4) + (((cu & 15) ^ (r & 15)) << 4);
    *reinterpret_cast<uint4*>(fb + byte) = pk;
  }
  __syncthreads();

  const int wid  = t >> 6;
  const int lane = t & 63;
  const int lrow = lane & 15;
  const int hi   = lane >> 4;

  const unsigned short* wp = wbf + lrow * IN_DIM + hi * 8;

  f32x4 acc[2][8];
#pragma unroll
  for (int s = 0; s < 2; ++s)
#pragma unroll
    for (int nt = 0; nt < 8; ++nt) acc[s][nt] = (f32x4){0.f, 0.f, 0.f, 0.f};

#pragma unroll
  for (int ks = 0; ks < 8; ++ks) {
    const int cu = ks * 4 + hi;  // 16B unit within the row
    bf16x8 b[2];
#pragma unroll
    for (int s = 0; s < 2; ++s) {
      const int rl = wid * 32 + s * 16 + lrow;
      const int byte =
          rl * 512 + ((cu & 16) << 4) + (((cu & 15) ^ (rl & 15)) << 4);
      b[s] = *reinterpret_cast<const bf16x8*>(fb + byte);
    }
#pragma unroll
    for (int nt = 0; nt < 8; ++nt) {
      const bf16x8 af =
          *reinterpret_cast<const bf16x8*>(wp + nt * 16 * IN_DIM + ks * 32);
      acc[0][nt] =
          __builtin_amdgcn_mfma_f32_16x16x32_bf16(af, b[0], acc[0][nt], 0, 0, 0);
      acc[1][nt] =
          __builtin_amdgcn_mfma_f32_16x16x32_bf16(af, b[1], acc[1][nt], 0, 0, 0);
    }
  }

#pragma unroll
  for (int s = 0; s < 2; ++s) {
    const int mrow = row0 + wid * 32 + s * 16 + lrow;
    if (mrow < nrows) {
      unsigned short* orow = support + mrow * OUT_DIM + hi * 4;
#pragma unroll
      for (int nt = 0; nt < 8; ++nt) {
        f32x4 v = acc[s][nt];
        float a0 = v[0] > 0.f ? v[0] : LEAKY * v[0];
        float a1 = v[1] > 0.f ? v[1] : LEAKY * v[1];
        float a2 = v[2] > 0.f ? v[2] : LEAKY * v[2];
        float a3 = v[3] > 0.f ? v[3] : LEAKY * v[3];
        uint2 st;
        st.x = cvtpk_bf16(a0, a1);
        st.y = cvtpk_bf16(a2, a3);
        *reinterpret_cast<uint2*>(orow + nt * 16) = st;
      }
    }
  }
}

// ---------------------------------------------------------------------------
// Kernel 2: out[r] = sum over edges (r,c,v) of v * support_bf16[c]
// Bounds come from precomputed row_starts (broadcast load, no barrier).
// 256 threads = 8 rows x 32 lanes; lane owns 4 cols (8B ushort4 gathers).
// UNROLL=8 predicated -> 8 gathers in flight per half-wave.
// ---------------------------------------------------------------------------
__global__ __launch_bounds__(256) void spmm_bf16(
    const int* __restrict__ rs, const int* __restrict__ ecols,
    const float* __restrict__ evals, const unsigned short* __restrict__ support,
    float* __restrict__ out, int nrows) {
  const int t    = threadIdx.x;
  const int row0 = blockIdx.x * 8;
  const int lr   = t >> 5;
  const int lane = t & 31;
  const int row  = row0 + lr;
  if (row >= nrows) return;

  const int s = rs[row];
  const int e = rs[row + 1];

  float4 acc[8];
#pragma unroll
  for (int j = 0; j < 8; ++j) acc[j] = (float4){0.f, 0.f, 0.f, 0.f};

  for (int i = s; i < e; i += 8) {
    int   ii[8];
    float vv[8];
#pragma unroll
    for (int j = 0; j < 8; ++j) {
      const int  idx = i + j;
      const bool ok  = idx < e;
      ii[j] = ok ? idx : e - 1;
      vv[j] = ok ? evals[ii[j]] : 0.f;
    }
#pragma unroll
    for (int j = 0; j < 8; ++j) {
      const int c = ecols[ii[j]];
      const ushort4 u =
          *reinterpret_cast<const ushort4*>(&support[c * OUT_DIM + lane * 4]);
      acc[j].x += vv[j] * b2f(u.x);
      acc[j].y += vv[j] * b2f(u.y);
      acc[j].z += vv[j] * b2f(u.z);
      acc[j].w += vv[j] * b2f(u.w);
    }
  }

#pragma unroll
  for (int j = 1; j < 8; ++j) {
    acc[0].x += acc[j].x;
    acc[0].y += acc[j].y;
    acc[0].z += acc[j].z;
    acc[0].w += acc[j].w;
  }
  *reinterpret_cast<float4*>(&out[row * OUT_DIM + lane * 4]) = acc[0];
}

// ---------------------------------------------------------------------------
extern "C" void kernel_launch(void* const* d_in, const int* in_sizes, int n_in,
                              void* d_out, int out_size, void* d_ws,
                              size_t ws_size, hipStream_t stream) {
  const float* features = (const float*)d_in[0];
  const float* weight   = (const float*)d_in[1];
  const int*   erows    = (const int*)d_in[2];
  const int*   ecols    = (const int*)d_in[3];
  const float* evals    = (const float*)d_in[4];
  float*       out      = (float*)d_out;

  const int nrows  = in_sizes[0] / IN_DIM;  // 100000
  const int nedges = in_sizes[2];           // 1600000

  // ws layout: support bf16 (25.6 MB) | wbf16 (64 KB) | row_starts (400 KB)
  unsigned short* support = (unsigned short*)d_ws;
  unsigned short* wbf =
      (unsigned short*)((char*)d_ws + (size_t)nrows * OUT_DIM * 2);
  int* rs = (int*)((char*)wbf + (size_t)OUT_DIM * IN_DIM * 2);

  wcvt<<<64, 256, 0, stream>>>(weight, (unsigned*)wbf);
  row_bounds<<<(nrows + 256) / 256, 256, 0, stream>>>(erows, rs, nrows, nedges);
  gemm_mfma<<<(nrows + 127) / 128, 256, 0, stream>>>(features, wbf, support,
                                                     nrows);
  spmm_bf16<<<(nrows + 7) / 8, 256, 0, stream>>>(rs, ecols, evals, support,
                                                 out, nrows);
}